// Round 2
// baseline (6740.635 us; speedup 1.0000x reference)
//
#include <hip/hip_runtime.h>
#include <stdint.h>

#define TSEQ 256
#define NB   128

typedef unsigned short u16;
typedef unsigned int   u32;
typedef __attribute__((ext_vector_type(8))) short short8;  // 8 x bf16 (4 VGPRs)
typedef __attribute__((ext_vector_type(4))) float fx4;
typedef __attribute__((ext_vector_type(4))) u32  ux4;
typedef __attribute__((ext_vector_type(2))) u32  ux2;

static __device__ __forceinline__ u16 f2bf(float f){
  u32 u = __float_as_uint(f);
  u32 r = ((u >> 16) & 1u) + 0x7fffu;   // round-to-nearest-even
  return (u16)((u + r) >> 16);
}
static __device__ __forceinline__ float bf2f(u32 h){ return __uint_as_float(h << 16); }
static __device__ __forceinline__ float sigf(float x){ return 1.0f / (1.0f + __expf(-x)); }
static __device__ __forceinline__ float tanh_(float x){
  float ax = fabsf(x);
  float e  = __expf(-2.0f * ax);
  float t  = (1.0f - e) / (1.0f + e);
  return copysignf(t, x);
}

// ---------------- grid barrier (persistent kernel, 256 co-resident WGs) ----------------
static __device__ __forceinline__ void gbar(u32* bar, u32 target){
  __syncthreads();                       // all waves of this WG drain their stores
  if (threadIdx.x == 0){
    __hip_atomic_fetch_add(bar, 1u, __ATOMIC_RELEASE, __HIP_MEMORY_SCOPE_AGENT);
    while (__hip_atomic_load(bar, __ATOMIC_RELAXED, __HIP_MEMORY_SCOPE_AGENT) < target)
      __builtin_amdgcn_s_sleep(1);
    __builtin_amdgcn_fence(__ATOMIC_ACQUIRE, "agent");   // inv L1 (covers whole CU/WG)
  }
  __syncthreads();
}

// ---------------- embedding gather + fp32->bf16 ----------------
__global__ __launch_bounds__(256) void k_embed(const int* __restrict__ tok,
                                               const float* __restrict__ tab,
                                               u16* __restrict__ embA){
  const int row  = blockIdx.x * 4 + (threadIdx.x >> 6);   // row = t*128 + b
  const int lane = threadIdx.x & 63;
  const int t = row >> 7;
  const int b = row & 127;
  const int tk = tok[b * TSEQ + t];
  const float* src = tab + (long)tk * 512 + lane * 8;
  const fx4 f0 = *(const fx4*)src;
  const fx4 f1 = *(const fx4*)(src + 4);
  ux4 w;
  w[0] = (u32)f2bf(f0[0]) | ((u32)f2bf(f0[1]) << 16);
  w[1] = (u32)f2bf(f0[2]) | ((u32)f2bf(f0[3]) << 16);
  w[2] = (u32)f2bf(f1[0]) | ((u32)f2bf(f1[1]) << 16);
  w[3] = (u32)f2bf(f1[2]) | ((u32)f2bf(f1[3]) << 16);
  *(ux4*)(embA + (long)row * 512 + lane * 8) = w;
}

// ---------------- tiled transpose fp32(RxC) -> bf16(CxR) ----------------
__global__ __launch_bounds__(256) void k_transpose(const float* __restrict__ in,
                                                   u16* __restrict__ out, int R, int C){
  __shared__ float tile[32][33];
  const int c0 = blockIdx.x * 32;
  const int r0 = blockIdx.y * 32;
  const int tx = threadIdx.x;   // 0..31
  const int ty = threadIdx.y;   // 0..7
#pragma unroll
  for (int i = 0; i < 4; ++i)
    tile[ty + i * 8][tx] = in[(long)(r0 + ty + i * 8) * C + c0 + tx];
  __syncthreads();
#pragma unroll
  for (int i = 0; i < 4; ++i)
    out[(long)(c0 + ty + i * 8) * R + r0 + tx] = f2bf(tile[tx][ty + i * 8]);
}

// ---------------- persistent bidirectional LSTM with fused x-projection ----------------
// 256 WGs x 256 thr. WG = (dir, batch-half(64), 16 h -> 64 gate cols).
// Wave = (batch-32-half bh2) x (K-half kh). Wh B-frags persistent in 256 VGPRs.
// Per step: [pre-barrier] Wx GEMM from embA/WxT (no H dependency, hides in barrier wait)
//           [post-barrier] Wh GEMM on H(t-1), elementwise, H(t) store.
__global__ __launch_bounds__(256, 1) void k_recurrent(
    const u16* __restrict__ embA,                        // (T*B, 512) bf16
    const u16* __restrict__ WxT,                         // (2*4096, 512) bf16 (f then b)
    const u16* __restrict__ WhfT, const u16* __restrict__ WhbT,   // (4096,1024) bf16
    const float* __restrict__ bhf, const float* __restrict__ bhb,
    u16* __restrict__ Hbuf,                              // [2 dir][2 buf][128][1024] bf16
    float* __restrict__ pooled,                          // [128][2048] fp32 (relu'd)
    u32* __restrict__ bar)
{
  __shared__ float P[2][64][68];
  const int tid  = threadIdx.x;
  const int lane = tid & 63;
  const int wid  = tid >> 6;
  const int bx   = blockIdx.x;
  const int dir  = bx >> 7;
  const int bh   = (bx >> 6) & 1;
  const int ch   = bx & 63;
  const int h0   = ch * 16;
  const int b0   = bh * 64;
  const int bh2  = wid >> 1;
  const int kh   = wid & 1;
  const int l15  = lane & 15, l4 = lane >> 4;

  const u16*   WhT  = dir ? WhbT : WhfT;
  const float* bias = dir ? bhb : bhf;

  // persistent Wh weight fragments: this wave's 64 cols x 512-K half (256 VGPRs)
  short8 Bfr[16][4];
#pragma unroll
  for (int w = 0; w < 16; ++w)
#pragma unroll
    for (int g = 0; g < 4; ++g)
      Bfr[w][g] = *(const short8*)(WhT + (long)(g * 1024 + h0 + l15) * 1024
                                       + kh * 512 + w * 32 + l4 * 8);

  // Wx row pointers (B-operand of the x-projection GEMM)
  const u16* rowBx[4];
#pragma unroll
  for (int g = 0; g < 4; ++g)
    rowBx[g] = WxT + ((long)dir * 4096 + g * 1024 + h0 + l15) * 512 + kh * 256 + l4 * 8;

  const int bl = tid >> 2;               // local batch 0..63
  const int q  = tid & 3;                // h-quad
  const int bg = b0 + bl;

  fx4 bsv[4];
#pragma unroll
  for (int g = 0; g < 4; ++g)
    bsv[g] = *(const fx4*)(bias + g * 1024 + h0 + q * 4);

  {  // zero the "previous H" buffer (buf index 1, read at t=0)
    u16* z = Hbuf + (((long)dir * 2 + 1) * 128 + bg) * 1024 + h0 + q * 4;
    ux2 zz; zz[0] = 0u; zz[1] = 0u;
    *(ux2*)z = zz;
  }

  float Creg[4] = {0.f, 0.f, 0.f, 0.f};
  float pmax[4] = {-3.0e38f, -3.0e38f, -3.0e38f, -3.0e38f};

  fx4 acc[2][4];
#pragma unroll
  for (int fm = 0; fm < 2; ++fm)
#pragma unroll
    for (int g = 0; g < 4; ++g)
#pragma unroll
      for (int r = 0; r < 4; ++r) acc[fm][g][r] = 0.f;

  // x-projection for step tt accumulated into acc (no H dependency)
  auto prefetch_x = [&](int tt){
    const long er = (long)(dir ? (TSEQ - 1 - tt) : tt) * NB + b0 + bh2 * 32;
    const u16* rowA0 = embA + (er + l15) * 512 + kh * 256 + l4 * 8;
    const u16* rowA1 = rowA0 + 16 * 512;
#pragma unroll
    for (int w = 0; w < 8; ++w){
      short8 ax0 = *(const short8*)(rowA0 + w * 32);
      short8 ax1 = *(const short8*)(rowA1 + w * 32);
#pragma unroll
      for (int g = 0; g < 4; ++g){
        short8 bx = *(const short8*)(rowBx[g] + w * 32);
        acc[0][g] = __builtin_amdgcn_mfma_f32_16x16x32_bf16(ax0, bx, acc[0][g], 0, 0, 0);
        acc[1][g] = __builtin_amdgcn_mfma_f32_16x16x32_bf16(ax1, bx, acc[1][g], 0, 0, 0);
      }
    }
  };

  prefetch_x(0);
  u32 bt = 256;
  gbar(bar, bt); bt += 256;              // H zeros (and prior kernels) visible everywhere

  for (int t = 0; t < TSEQ; ++t){
    const int rdb = (t + 1) & 1;
    const int wrb = t & 1;

    // Wh GEMM on H(t-1): 32 rows x 64 cols over this wave's 512-K half
    const u16* rowH0 = Hbuf + (((long)dir * 2 + rdb) * 128 + b0 + bh2 * 32 + l15) * 1024
                            + kh * 512 + l4 * 8;
    const u16* rowH1 = rowH0 + 16 * 1024;
#pragma unroll
    for (int w = 0; w < 16; ++w){
      short8 a0 = *(const short8*)(rowH0 + w * 32);
      short8 a1 = *(const short8*)(rowH1 + w * 32);
#pragma unroll
      for (int g = 0; g < 4; ++g){
        acc[0][g] = __builtin_amdgcn_mfma_f32_16x16x32_bf16(a0, Bfr[w][g], acc[0][g], 0, 0, 0);
        acc[1][g] = __builtin_amdgcn_mfma_f32_16x16x32_bf16(a1, Bfr[w][g], acc[1][g], 0, 0, 0);
      }
    }

#pragma unroll
    for (int fm = 0; fm < 2; ++fm)
#pragma unroll
      for (int g = 0; g < 4; ++g)
#pragma unroll
        for (int r = 0; r < 4; ++r)
          P[kh][bh2 * 32 + fm * 16 + l4 * 4 + r][g * 16 + l15] = acc[fm][g][r];

    __syncthreads();

    // elementwise: thread owns (1 batch x 4 h); C and running max in registers
    float gv[4][4];
#pragma unroll
    for (int g = 0; g < 4; ++g){
      const fx4 p0 = *(const fx4*)&P[0][bl][g * 16 + q * 4];
      const fx4 p1 = *(const fx4*)&P[1][bl][g * 16 + q * 4];
#pragma unroll
      for (int j = 0; j < 4; ++j) gv[g][j] = p0[j] + p1[j] + bsv[g][j];
    }

    u16 hb[4];
#pragma unroll
    for (int j = 0; j < 4; ++j){
      float i_, f_, o_;
      if (dir == 0){
        i_ = sigf(gv[0][j]); f_ = sigf(gv[1][j]); o_ = sigf(gv[2][j]);
      } else {  // reference applies sigmoid twice on backward i/f/o
        i_ = sigf(sigf(gv[0][j])); f_ = sigf(sigf(gv[1][j])); o_ = sigf(sigf(gv[2][j]));
      }
      const float cn = tanh_(gv[3][j]);
      Creg[j] = f_ * Creg[j] + i_ * cn;
      const float h = o_ * tanh_(Creg[j]);
      pmax[j] = fmaxf(pmax[j], h);
      hb[j] = f2bf(h);
    }
    {
      u16* hw = Hbuf + (((long)dir * 2 + wrb) * 128 + bg) * 1024 + h0 + q * 4;
      ux2 pk; pk[0] = (u32)hb[0] | ((u32)hb[1] << 16);
              pk[1] = (u32)hb[2] | ((u32)hb[3] << 16);
      *(ux2*)hw = pk;
    }

    // reset acc and pre-compute next step's x-projection while waiting at the barrier
#pragma unroll
    for (int fm = 0; fm < 2; ++fm)
#pragma unroll
      for (int g = 0; g < 4; ++g)
#pragma unroll
        for (int r = 0; r < 4; ++r) acc[fm][g][r] = 0.f;
    if (t + 1 < TSEQ) prefetch_x(t + 1);

    gbar(bar, bt); bt += 256;
  }

  {  // relu(maxpool) in fp32 for the MLP head
    float* pw = pooled + (long)bg * 2048 + dir * 1024 + h0 + q * 4;
    fx4 pv;
#pragma unroll
    for (int j = 0; j < 4; ++j) pv[j] = fmaxf(pmax[j], 0.f);
    *(fx4*)pw = pv;
  }
}

// ---------------- MLP layer 1 (fp32): h = relu(pooled) @ W1 + b1 ----------------
__global__ __launch_bounds__(256) void k_mlp1(const float* __restrict__ pooled,
                                              const float* __restrict__ W1,
                                              const float* __restrict__ b1,
                                              float* __restrict__ hbuf){
  const int cb = blockIdx.x & 7, bb = blockIdx.x >> 3;
  const int c  = cb * 64 + (threadIdx.x & 63);
  const int bq = threadIdx.x >> 6;
  const int b0 = bb * 16 + bq * 4;
  float a0 = 0.f, a1 = 0.f, a2 = 0.f, a3 = 0.f;
  for (int k = 0; k < 2048; k += 4){
    const fx4 p0 = *(const fx4*)(pooled + (long)(b0 + 0) * 2048 + k);
    const fx4 p1 = *(const fx4*)(pooled + (long)(b0 + 1) * 2048 + k);
    const fx4 p2 = *(const fx4*)(pooled + (long)(b0 + 2) * 2048 + k);
    const fx4 p3 = *(const fx4*)(pooled + (long)(b0 + 3) * 2048 + k);
#pragma unroll
    for (int j = 0; j < 4; ++j){
      const float w = W1[(long)(k + j) * 512 + c];
      a0 += p0[j] * w; a1 += p1[j] * w; a2 += p2[j] * w; a3 += p3[j] * w;
    }
  }
  const float bv = b1[c];
  hbuf[(long)(b0 + 0) * 512 + c] = a0 + bv;
  hbuf[(long)(b0 + 1) * 512 + c] = a1 + bv;
  hbuf[(long)(b0 + 2) * 512 + c] = a2 + bv;
  hbuf[(long)(b0 + 3) * 512 + c] = a3 + bv;
}

// ---------------- MLP layer 2 (fp32): out = h @ W2 + b2 ----------------
__global__ __launch_bounds__(64) void k_mlp2(const float* __restrict__ hbuf,
                                             const float* __restrict__ W2,
                                             const float* __restrict__ b2,
                                             float* __restrict__ out){
  const int idx = blockIdx.x * 64 + threadIdx.x;
  if (idx >= 640) return;
  const int b = idx / 5;
  const int j = idx % 5;
  float sum = b2[j];
  for (int c = 0; c < 512; ++c)
    sum += hbuf[(long)b * 512 + c] * W2[c * 5 + j];
  out[idx] = sum;
}

extern "C" void kernel_launch(void* const* d_in, const int* in_sizes, int n_in,
                              void* d_out, int out_size, void* d_ws, size_t ws_size,
                              hipStream_t stream){
  const int*   inputs = (const int*)d_in[0];
  const float* emb_tb = (const float*)d_in[1];
  const float* Wxf = (const float*)d_in[2];
  const float* Whf = (const float*)d_in[3];
  const float* bhf = (const float*)d_in[4];
  const float* Wxb = (const float*)d_in[5];
  const float* Whb = (const float*)d_in[6];
  const float* bhb = (const float*)d_in[7];
  const float* W1  = (const float*)d_in[8];
  const float* b1  = (const float*)d_in[9];
  const float* W2  = (const float*)d_in[10];
  const float* b2  = (const float*)d_in[11];
  float* out = (float*)d_out;

  char* ws = (char*)d_ws;
  size_t off = 0;
  auto alloc = [&](size_t bytes)->char*{
    char* p = ws + off; off = (off + bytes + 511) & ~(size_t)511; return p;
  };
  u32*   bar    = (u32*)alloc(512);
  u16*   embA   = (u16*)alloc((size_t)32768 * 512 * 2);        // 32 MB
  u16*   WhfT   = (u16*)alloc((size_t)4096 * 1024 * 2);        //  8 MB
  u16*   WhbT   = (u16*)alloc((size_t)4096 * 1024 * 2);        //  8 MB
  u16*   WxT    = (u16*)alloc((size_t)8192 * 512 * 2);         //  8 MB
  u16*   Hbuf   = (u16*)alloc((size_t)2 * 2 * 128 * 1024 * 2); //  1 MB
  float* pooled = (float*)alloc((size_t)128 * 2048 * 4);       //  1 MB
  float* hbuf   = (float*)alloc((size_t)128 * 512 * 4);        // .25 MB
  // total ~58.5 MB

  hipMemsetAsync(bar, 0, 64, stream);
  k_embed<<<8192, 256, 0, stream>>>(inputs, emb_tb, embA);
  k_transpose<<<dim3(128, 32), dim3(32, 8), 0, stream>>>(Whf, WhfT, 1024, 4096);
  k_transpose<<<dim3(128, 32), dim3(32, 8), 0, stream>>>(Whb, WhbT, 1024, 4096);
  k_transpose<<<dim3(128, 16), dim3(32, 8), 0, stream>>>(Wxf, WxT, 512, 4096);
  k_transpose<<<dim3(128, 16), dim3(32, 8), 0, stream>>>(Wxb, WxT + (size_t)4096 * 512, 512, 4096);
  k_recurrent<<<256, 256, 0, stream>>>(embA, WxT, WhfT, WhbT, bhf, bhb, Hbuf, pooled, bar);
  k_mlp1<<<64, 256, 0, stream>>>(pooled, W1, b1, hbuf);
  k_mlp2<<<10, 64, 0, stream>>>(hbuf, W2, b2, out);
}

// Round 3
// 4224.411 us; speedup vs baseline: 1.5956x; 1.5956x over previous
//
#include <hip/hip_runtime.h>
#include <stdint.h>

#define TSEQ 256
#define NB   128

typedef unsigned short u16;
typedef unsigned int   u32;
typedef unsigned long long u64;
typedef __attribute__((ext_vector_type(8))) short short8;  // 8 x bf16 (4 VGPRs)
typedef __attribute__((ext_vector_type(4))) float fx4;
typedef __attribute__((ext_vector_type(4))) u32  ux4;

static __device__ __forceinline__ u16 f2bf(float f){
  u32 u = __float_as_uint(f);
  u32 r = ((u >> 16) & 1u) + 0x7fffu;   // round-to-nearest-even
  return (u16)((u + r) >> 16);
}
static __device__ __forceinline__ float sigf(float x){ return 1.0f / (1.0f + __expf(-x)); }
static __device__ __forceinline__ float tanh_(float x){
  float ax = fabsf(x);
  float e  = __expf(-2.0f * ax);
  float t  = (1.0f - e) / (1.0f + e);
  return copysignf(t, x);
}

// device-coherent (cross-XCD) 16B H-fragment load as two 8B agent-scope atomics
static __device__ __forceinline__ short8 ld_h16(const u16* p){
  u64 lo = __hip_atomic_load((u64*)p,       __ATOMIC_RELAXED, __HIP_MEMORY_SCOPE_AGENT);
  u64 hi = __hip_atomic_load((u64*)(p + 4), __ATOMIC_RELAXED, __HIP_MEMORY_SCOPE_AGENT);
  union { u64 q[2]; short8 s; } u;
  u.q[0] = lo; u.q[1] = hi;
  return u.s;
}

// ---------------- embedding gather + fp32->bf16 ----------------
__global__ __launch_bounds__(256) void k_embed(const int* __restrict__ tok,
                                               const float* __restrict__ tab,
                                               u16* __restrict__ embA){
  const int row  = blockIdx.x * 4 + (threadIdx.x >> 6);   // row = t*128 + b
  const int lane = threadIdx.x & 63;
  const int t = row >> 7;
  const int b = row & 127;
  const int tk = tok[b * TSEQ + t];
  const float* src = tab + (long)tk * 512 + lane * 8;
  const fx4 f0 = *(const fx4*)src;
  const fx4 f1 = *(const fx4*)(src + 4);
  ux4 w;
  w[0] = (u32)f2bf(f0[0]) | ((u32)f2bf(f0[1]) << 16);
  w[1] = (u32)f2bf(f0[2]) | ((u32)f2bf(f0[3]) << 16);
  w[2] = (u32)f2bf(f1[0]) | ((u32)f2bf(f1[1]) << 16);
  w[3] = (u32)f2bf(f1[2]) | ((u32)f2bf(f1[3]) << 16);
  *(ux4*)(embA + (long)row * 512 + lane * 8) = w;
}

// ---------------- tiled transpose fp32(RxC) -> bf16(CxR) ----------------
__global__ __launch_bounds__(256) void k_transpose(const float* __restrict__ in,
                                                   u16* __restrict__ out, int R, int C){
  __shared__ float tile[32][33];
  const int c0 = blockIdx.x * 32;
  const int r0 = blockIdx.y * 32;
  const int tx = threadIdx.x;   // 0..31
  const int ty = threadIdx.y;   // 0..7
#pragma unroll
  for (int i = 0; i < 4; ++i)
    tile[ty + i * 8][tx] = in[(long)(r0 + ty + i * 8) * C + c0 + tx];
  __syncthreads();
#pragma unroll
  for (int i = 0; i < 4; ++i)
    out[(long)(c0 + ty + i * 8) * R + r0 + tx] = f2bf(tile[tx][ty + i * 8]);
}

// ---------------- persistent bidirectional LSTM with fused x-projection ----------------
// 256 WGs x 256 thr, 1 WG/CU. WG = (dir, batch-half(64), 16 h -> 64 gate cols).
// Wave = (batch-32-half bh2) x (K-half kh). Wh B-frags persistent in registers.
// Only H crosses WGs per step -> H uses agent-scope (cross-XCD coherent) atomics;
// all other streams (embA, WxT, Wh) stay hot in L1/L2: NO acquire fence / buffer_inv.
__global__ __launch_bounds__(256, 1) void k_recurrent(
    const u16* __restrict__ embA,                        // (T*B, 512) bf16
    const u16* __restrict__ WxT,                         // (2*4096, 512) bf16 (f then b)
    const u16* __restrict__ WhfT, const u16* __restrict__ WhbT,   // (4096,1024) bf16
    const float* __restrict__ bhf, const float* __restrict__ bhb,
    u16* __restrict__ Hbuf,                              // [2 dir][2 buf][128][1024] bf16
    float* __restrict__ pooled,                          // [128][2048] fp32 (relu'd)
    u32* __restrict__ bar)
{
  __shared__ float P[2][64][68];
  const int tid  = threadIdx.x;
  const int lane = tid & 63;
  const int wid  = tid >> 6;
  const int bx   = blockIdx.x;
  const int dir  = bx >> 7;
  const int bh   = (bx >> 6) & 1;
  const int ch   = bx & 63;
  const int h0   = ch * 16;
  const int b0   = bh * 64;
  const int bh2  = wid >> 1;
  const int kh   = wid & 1;
  const int l15  = lane & 15, l4 = lane >> 4;

  const u16*   WhT  = dir ? WhbT : WhfT;
  const float* bias = dir ? bhb : bhf;

  // persistent Wh weight fragments: this wave's 64 cols x 512-K half
  short8 Bfr[16][4];
#pragma unroll
  for (int w = 0; w < 16; ++w)
#pragma unroll
    for (int g = 0; g < 4; ++g)
      Bfr[w][g] = *(const short8*)(WhT + (long)(g * 1024 + h0 + l15) * 1024
                                       + kh * 512 + w * 32 + l4 * 8);

  // Wx row pointers (B-operand of the x-projection GEMM)
  const u16* rowBx[4];
#pragma unroll
  for (int g = 0; g < 4; ++g)
    rowBx[g] = WxT + ((long)dir * 4096 + g * 1024 + h0 + l15) * 512 + kh * 256 + l4 * 8;

  const int bl = tid >> 2;               // local batch 0..63
  const int q  = tid & 3;                // h-quad
  const int bg = b0 + bl;

  fx4 bsv[4];
#pragma unroll
  for (int g = 0; g < 4; ++g)
    bsv[g] = *(const fx4*)(bias + g * 1024 + h0 + q * 4);

  float Creg[4] = {0.f, 0.f, 0.f, 0.f};
  float pmax[4] = {-3.0e38f, -3.0e38f, -3.0e38f, -3.0e38f};

  fx4 acc[2][4];
#pragma unroll
  for (int fm = 0; fm < 2; ++fm)
#pragma unroll
    for (int g = 0; g < 4; ++g)
#pragma unroll
      for (int r = 0; r < 4; ++r) acc[fm][g][r] = 0.f;

  // x-projection for step tt accumulated into acc (no H dependency; L2-hot)
  auto prefetch_x = [&](int tt){
    const long er = (long)(dir ? (TSEQ - 1 - tt) : tt) * NB + b0 + bh2 * 32;
    const u16* rowA0 = embA + (er + l15) * 512 + kh * 256 + l4 * 8;
    const u16* rowA1 = rowA0 + 16 * 512;
#pragma unroll
    for (int w = 0; w < 8; ++w){
      short8 ax0 = *(const short8*)(rowA0 + w * 32);
      short8 ax1 = *(const short8*)(rowA1 + w * 32);
#pragma unroll
      for (int g = 0; g < 4; ++g){
        short8 bx = *(const short8*)(rowBx[g] + w * 32);
        acc[0][g] = __builtin_amdgcn_mfma_f32_16x16x32_bf16(ax0, bx, acc[0][g], 0, 0, 0);
        acc[1][g] = __builtin_amdgcn_mfma_f32_16x16x32_bf16(ax1, bx, acc[1][g], 0, 0, 0);
      }
    }
  };

  prefetch_x(0);

  for (int t = 0; t < TSEQ; ++t){
    const int rdb = (t + 1) & 1;
    const int wrb = t & 1;

    if (t > 0){
      // Wh GEMM on H(t-1): 32 rows x 64 cols over this wave's 512-K half.
      // H loads are agent-scope (bypass L1/L2 -> coherence point).
      const u16* rowH0 = Hbuf + (((long)dir * 2 + rdb) * 128 + b0 + bh2 * 32 + l15) * 1024
                              + kh * 512 + l4 * 8;
      const u16* rowH1 = rowH0 + 16 * 1024;
#pragma unroll
      for (int w = 0; w < 16; ++w){
        short8 a0 = ld_h16(rowH0 + w * 32);
        short8 a1 = ld_h16(rowH1 + w * 32);
#pragma unroll
        for (int g = 0; g < 4; ++g){
          acc[0][g] = __builtin_amdgcn_mfma_f32_16x16x32_bf16(a0, Bfr[w][g], acc[0][g], 0, 0, 0);
          acc[1][g] = __builtin_amdgcn_mfma_f32_16x16x32_bf16(a1, Bfr[w][g], acc[1][g], 0, 0, 0);
        }
      }
    }

#pragma unroll
    for (int fm = 0; fm < 2; ++fm)
#pragma unroll
      for (int g = 0; g < 4; ++g)
#pragma unroll
        for (int r = 0; r < 4; ++r)
          P[kh][bh2 * 32 + fm * 16 + l4 * 4 + r][g * 16 + l15] = acc[fm][g][r];

    __syncthreads();

    // elementwise: thread owns (1 batch x 4 h); C and running max in registers
    float gv[4][4];
#pragma unroll
    for (int g = 0; g < 4; ++g){
      const fx4 p0 = *(const fx4*)&P[0][bl][g * 16 + q * 4];
      const fx4 p1 = *(const fx4*)&P[1][bl][g * 16 + q * 4];
#pragma unroll
      for (int j = 0; j < 4; ++j) gv[g][j] = p0[j] + p1[j] + bsv[g][j];
    }

    u16 hb[4];
#pragma unroll
    for (int j = 0; j < 4; ++j){
      float i_, f_, o_;
      if (dir == 0){
        i_ = sigf(gv[0][j]); f_ = sigf(gv[1][j]); o_ = sigf(gv[2][j]);
      } else {  // reference applies sigmoid twice on backward i/f/o
        i_ = sigf(sigf(gv[0][j])); f_ = sigf(sigf(gv[1][j])); o_ = sigf(sigf(gv[2][j]));
      }
      const float cn = tanh_(gv[3][j]);
      Creg[j] = f_ * Creg[j] + i_ * cn;
      const float h = o_ * tanh_(Creg[j]);
      pmax[j] = fmaxf(pmax[j], h);
      hb[j] = f2bf(h);
    }
    {  // H(t) store: agent-scope (visible at device coherence point)
      u16* hw = Hbuf + (((long)dir * 2 + wrb) * 128 + bg) * 1024 + h0 + q * 4;
      u64 pk = (u64)hb[0] | ((u64)hb[1] << 16) | ((u64)hb[2] << 32) | ((u64)hb[3] << 48);
      __hip_atomic_store((u64*)hw, pk, __ATOMIC_RELAXED, __HIP_MEMORY_SCOPE_AGENT);
    }

    if (t + 1 < TSEQ){
      // split grid barrier: arrive, overlap next-x prefetch, then wait
      __syncthreads();   // drains every wave's H stores (vmcnt(0) before s_barrier)
      if (tid == 0)
        __hip_atomic_fetch_add(bar, 1u, __ATOMIC_RELAXED, __HIP_MEMORY_SCOPE_AGENT);

#pragma unroll
      for (int fm = 0; fm < 2; ++fm)
#pragma unroll
        for (int g = 0; g < 4; ++g)
#pragma unroll
          for (int r = 0; r < 4; ++r) acc[fm][g][r] = 0.f;
      prefetch_x(t + 1);

      if (tid == 0){
        const u32 target = (u32)(t + 1) * 256u;
        while (__hip_atomic_load(bar, __ATOMIC_RELAXED, __HIP_MEMORY_SCOPE_AGENT) < target)
          __builtin_amdgcn_s_sleep(2);
      }
      __asm__ volatile("" ::: "memory");
      __syncthreads();
    }
  }

  {  // relu(maxpool) in fp32 for the MLP head
    float* pw = pooled + (long)bg * 2048 + dir * 1024 + h0 + q * 4;
    fx4 pv;
#pragma unroll
    for (int j = 0; j < 4; ++j) pv[j] = fmaxf(pmax[j], 0.f);
    *(fx4*)pw = pv;
  }
}

// ---------------- MLP layer 1 (fp32): h = relu(pooled) @ W1 + b1 ----------------
__global__ __launch_bounds__(256) void k_mlp1(const float* __restrict__ pooled,
                                              const float* __restrict__ W1,
                                              const float* __restrict__ b1,
                                              float* __restrict__ hbuf){
  const int cb = blockIdx.x & 7, bb = blockIdx.x >> 3;
  const int c  = cb * 64 + (threadIdx.x & 63);
  const int bq = threadIdx.x >> 6;
  const int b0 = bb * 16 + bq * 4;
  float a0 = 0.f, a1 = 0.f, a2 = 0.f, a3 = 0.f;
  for (int k = 0; k < 2048; k += 4){
    const fx4 p0 = *(const fx4*)(pooled + (long)(b0 + 0) * 2048 + k);
    const fx4 p1 = *(const fx4*)(pooled + (long)(b0 + 1) * 2048 + k);
    const fx4 p2 = *(const fx4*)(pooled + (long)(b0 + 2) * 2048 + k);
    const fx4 p3 = *(const fx4*)(pooled + (long)(b0 + 3) * 2048 + k);
#pragma unroll
    for (int j = 0; j < 4; ++j){
      const float w = W1[(long)(k + j) * 512 + c];
      a0 += p0[j] * w; a1 += p1[j] * w; a2 += p2[j] * w; a3 += p3[j] * w;
    }
  }
  const float bv = b1[c];
  hbuf[(long)(b0 + 0) * 512 + c] = a0 + bv;
  hbuf[(long)(b0 + 1) * 512 + c] = a1 + bv;
  hbuf[(long)(b0 + 2) * 512 + c] = a2 + bv;
  hbuf[(long)(b0 + 3) * 512 + c] = a3 + bv;
}

// ---------------- MLP layer 2 (fp32): out = h @ W2 + b2 ----------------
__global__ __launch_bounds__(64) void k_mlp2(const float* __restrict__ hbuf,
                                             const float* __restrict__ W2,
                                             const float* __restrict__ b2,
                                             float* __restrict__ out){
  const int idx = blockIdx.x * 64 + threadIdx.x;
  if (idx >= 640) return;
  const int b = idx / 5;
  const int j = idx % 5;
  float sum = b2[j];
  for (int c = 0; c < 512; ++c)
    sum += hbuf[(long)b * 512 + c] * W2[c * 5 + j];
  out[idx] = sum;
}

extern "C" void kernel_launch(void* const* d_in, const int* in_sizes, int n_in,
                              void* d_out, int out_size, void* d_ws, size_t ws_size,
                              hipStream_t stream){
  const int*   inputs = (const int*)d_in[0];
  const float* emb_tb = (const float*)d_in[1];
  const float* Wxf = (const float*)d_in[2];
  const float* Whf = (const float*)d_in[3];
  const float* bhf = (const float*)d_in[4];
  const float* Wxb = (const float*)d_in[5];
  const float* Whb = (const float*)d_in[6];
  const float* bhb = (const float*)d_in[7];
  const float* W1  = (const float*)d_in[8];
  const float* b1  = (const float*)d_in[9];
  const float* W2  = (const float*)d_in[10];
  const float* b2  = (const float*)d_in[11];
  float* out = (float*)d_out;

  char* ws = (char*)d_ws;
  size_t off = 0;
  auto alloc = [&](size_t bytes)->char*{
    char* p = ws + off; off = (off + bytes + 511) & ~(size_t)511; return p;
  };
  u32*   bar    = (u32*)alloc(512);
  u16*   embA   = (u16*)alloc((size_t)32768 * 512 * 2);        // 32 MB
  u16*   WhfT   = (u16*)alloc((size_t)4096 * 1024 * 2);        //  8 MB
  u16*   WhbT   = (u16*)alloc((size_t)4096 * 1024 * 2);        //  8 MB
  u16*   WxT    = (u16*)alloc((size_t)8192 * 512 * 2);         //  8 MB
  u16*   Hbuf   = (u16*)alloc((size_t)2 * 2 * 128 * 1024 * 2); //  1 MB
  float* pooled = (float*)alloc((size_t)128 * 2048 * 4);       //  1 MB
  float* hbuf   = (float*)alloc((size_t)128 * 512 * 4);        // .25 MB

  hipMemsetAsync(bar, 0, 64, stream);
  k_embed<<<8192, 256, 0, stream>>>(inputs, emb_tb, embA);
  k_transpose<<<dim3(128, 32), dim3(32, 8), 0, stream>>>(Whf, WhfT, 1024, 4096);
  k_transpose<<<dim3(128, 32), dim3(32, 8), 0, stream>>>(Whb, WhbT, 1024, 4096);
  k_transpose<<<dim3(128, 16), dim3(32, 8), 0, stream>>>(Wxf, WxT, 512, 4096);
  k_transpose<<<dim3(128, 16), dim3(32, 8), 0, stream>>>(Wxb, WxT + (size_t)4096 * 512, 512, 4096);
  k_recurrent<<<256, 256, 0, stream>>>(embA, WxT, WhfT, WhbT, bhf, bhb, Hbuf, pooled, bar);
  k_mlp1<<<64, 256, 0, stream>>>(pooled, W1, b1, hbuf);
  k_mlp2<<<10, 64, 0, stream>>>(hbuf, W2, b2, out);
}